// Round 1
// baseline (486.650 us; speedup 1.0000x reference)
//
#include <hip/hip_runtime.h>
#include <hip/hip_bf16.h>

#define D_DIM 1024
#define U_DIM 1024
#define B_SZ  32
#define T_SZ  2048

typedef __bf16 bf16x8 __attribute__((ext_vector_type(8)));
typedef float f32x4 __attribute__((ext_vector_type(4)));
typedef unsigned short ushort8 __attribute__((ext_vector_type(8)));
typedef unsigned short ushort4_t __attribute__((ext_vector_type(4)));

__device__ __forceinline__ unsigned short f2bf(float f) {
    union { float f; unsigned u; } v;
    v.f = f;
    unsigned r = v.u + 0x7fffu + ((v.u >> 16) & 1u);  // RNE
    return (unsigned short)(r >> 16);
}

// ---------------- K1: W2 [D,U] fp32 -> W2t [U,D] bf16 ----------------
__global__ __launch_bounds__(256) void w2_transpose(const float* __restrict__ W2,
                                                    unsigned short* __restrict__ W2t) {
    __shared__ float tile[32][33];
    int d0 = blockIdx.x * 32, u0 = blockIdx.y * 32;
    int tx = threadIdx.x, ty = threadIdx.y;  // 32 x 8
#pragma unroll
    for (int i = 0; i < 4; i++)
        tile[ty + 8 * i][tx] = W2[(size_t)(d0 + ty + 8 * i) * U_DIM + u0 + tx];
    __syncthreads();
#pragma unroll
    for (int i = 0; i < 4; i++)
        W2t[(size_t)(u0 + ty + 8 * i) * D_DIM + d0 + tx] = f2bf(tile[tx][ty + 8 * i]);
}

// ---------------- K2: qpb[b,u] = query@W1 + b1 + b2 (fp32) ----------------
__global__ __launch_bounds__(256) void qproj(const float* __restrict__ query,
                                             const float* __restrict__ W1,
                                             const float* __restrict__ b1,
                                             const float* __restrict__ b2,
                                             float* __restrict__ qpb) {
    int b = blockIdx.x;
    int u = blockIdx.y * 256 + threadIdx.x;
    float acc = b1[u] + b2[u];
    const float* q = query + (size_t)b * D_DIM;
#pragma unroll 4
    for (int d = 0; d < D_DIM; d++)
        acc += q[d] * W1[(size_t)d * U_DIM + u];
    qpb[(size_t)b * U_DIM + u] = acc;
}

// ---------------- K3: fused score GEMM ----------------
// scores[b*T+t] += sum_{u in tile} tanh( (values@W2)[t,u] + qpb[b,u] ) * Wv[u]
#define BM 128
#define BN 128
#define BK 32
#define LDST 40  // bf16 elems per LDS row (32 + 8 pad) -> 80B stride, ~2-way banks

__global__ __launch_bounds__(256) void score_gemm(const float* __restrict__ values,
                                                  const unsigned short* __restrict__ W2t,
                                                  const float* __restrict__ qpb,
                                                  const float* __restrict__ Wv,
                                                  float* __restrict__ scores) {
    __shared__ unsigned short Al[BM * LDST];
    __shared__ unsigned short Bl[BN * LDST];
    const int tid = threadIdx.x;
    const int row0 = blockIdx.x * BM;   // global (b*T+t) row
    const int u0 = blockIdx.y * BN;

    f32x4 areg[4];
    ushort8 breg[2];

    auto loadA = [&](int k0) {
#pragma unroll
        for (int j = 0; j < 4; j++) {
            int idx = tid + j * 256;
            int r = idx >> 3, c = idx & 7;
            areg[j] = *reinterpret_cast<const f32x4*>(values + (size_t)(row0 + r) * D_DIM + k0 + c * 4);
        }
    };
    auto loadB = [&](int k0) {
#pragma unroll
        for (int j = 0; j < 2; j++) {
            int idx = tid + j * 256;
            int r = idx >> 2, s = idx & 3;
            breg[j] = *reinterpret_cast<const ushort8*>(W2t + (size_t)(u0 + r) * D_DIM + k0 + s * 8);
        }
    };

    f32x4 acc[4][4] = {};
    const int lane = tid & 63, wave = tid >> 6;
    const int wt0 = (wave >> 1) * 64, wu0 = (wave & 1) * 64;
    const int lr = lane & 15, lk = lane >> 4;

    loadA(0);
    loadB(0);
    for (int k0 = 0; k0 < D_DIM; k0 += BK) {
        __syncthreads();
#pragma unroll
        for (int j = 0; j < 4; j++) {
            int idx = tid + j * 256;
            int r = idx >> 3, c = idx & 7;
            ushort4_t h;
            h.x = f2bf(areg[j].x);
            h.y = f2bf(areg[j].y);
            h.z = f2bf(areg[j].z);
            h.w = f2bf(areg[j].w);
            *reinterpret_cast<ushort4_t*>(&Al[r * LDST + c * 4]) = h;
        }
#pragma unroll
        for (int j = 0; j < 2; j++) {
            int idx = tid + j * 256;
            int r = idx >> 2, s = idx & 3;
            *reinterpret_cast<ushort8*>(&Bl[r * LDST + s * 8]) = breg[j];
        }
        __syncthreads();
        if (k0 + BK < D_DIM) {
            loadA(k0 + BK);
            loadB(k0 + BK);
        }
        bf16x8 af[4], bfr[4];
#pragma unroll
        for (int m = 0; m < 4; m++)
            af[m] = *reinterpret_cast<const bf16x8*>(&Al[(wt0 + m * 16 + lr) * LDST + lk * 8]);
#pragma unroll
        for (int n = 0; n < 4; n++)
            bfr[n] = *reinterpret_cast<const bf16x8*>(&Bl[(wu0 + n * 16 + lr) * LDST + lk * 8]);
#pragma unroll
        for (int m = 0; m < 4; m++)
#pragma unroll
            for (int n = 0; n < 4; n++)
                acc[m][n] = __builtin_amdgcn_mfma_f32_16x16x32_bf16(af[m], bfr[n], acc[m][n], 0, 0, 0);
    }

    // epilogue: tanh + dot with Wv, reduce over this tile's 128 u-columns
    const int b = row0 >> 11;  // row0 / T_SZ
    float qv[4], wvv[4];
#pragma unroll
    for (int n = 0; n < 4; n++) {
        int un = u0 + wu0 + n * 16 + lr;
        qv[n] = qpb[(size_t)b * U_DIM + un];
        wvv[n] = Wv[un];
    }
#pragma unroll
    for (int m = 0; m < 4; m++) {
        float s[4] = {0.f, 0.f, 0.f, 0.f};
#pragma unroll
        for (int n = 0; n < 4; n++) {
#pragma unroll
            for (int r = 0; r < 4; r++) {
                float x = acc[m][n][r] + qv[n];
                float e = __expf(2.0f * x);
                float th = 1.0f - 2.0f / (e + 1.0f);  // tanh, overflow-safe
                s[r] += th * wvv[n];
            }
        }
#pragma unroll
        for (int off = 1; off < 16; off <<= 1) {
#pragma unroll
            for (int r = 0; r < 4; r++) s[r] += __shfl_xor(s[r], off);
        }
        if (lr == 0) {
            int trow = row0 + wt0 + m * 16 + lk * 4;
#pragma unroll
            for (int r = 0; r < 4; r++) atomicAdd(&scores[trow + r], s[r]);
        }
    }
}

// ---------------- K4: softmax over T per batch ----------------
__global__ __launch_bounds__(256) void softmax_k(const float* __restrict__ scores,
                                                 float* __restrict__ wout) {
    int b = blockIdx.x, tid = threadIdx.x;
    int lane = tid & 63, wave = tid >> 6;
    __shared__ float redm[4], reds[4];
    float v[8];
    float mx = -3.4e38f;
#pragma unroll
    for (int i = 0; i < 8; i++) {
        v[i] = scores[(size_t)b * T_SZ + tid + i * 256];
        mx = fmaxf(mx, v[i]);
    }
#pragma unroll
    for (int off = 1; off < 64; off <<= 1) mx = fmaxf(mx, __shfl_xor(mx, off));
    if (lane == 0) redm[wave] = mx;
    __syncthreads();
    mx = fmaxf(fmaxf(redm[0], redm[1]), fmaxf(redm[2], redm[3]));
    float sum = 0.f;
#pragma unroll
    for (int i = 0; i < 8; i++) {
        v[i] = __expf(v[i] - mx);
        sum += v[i];
    }
#pragma unroll
    for (int off = 1; off < 64; off <<= 1) sum += __shfl_xor(sum, off);
    if (lane == 0) reds[wave] = sum;
    __syncthreads();
    sum = reds[0] + reds[1] + reds[2] + reds[3];
    float inv = 1.0f / sum;
#pragma unroll
    for (int i = 0; i < 8; i++) wout[(size_t)b * T_SZ + tid + i * 256] = v[i] * inv;
}

// ---------------- K5: context[b,d] = sum_t w[b,t] * values[b,t,d] ----------------
__global__ __launch_bounds__(256) void context_k(const float* __restrict__ values,
                                                 const float* __restrict__ w,
                                                 float* __restrict__ out) {
    int b = blockIdx.x, tc = blockIdx.y;
    int d4 = threadIdx.x;
    f32x4 acc = {0.f, 0.f, 0.f, 0.f};
    const float* vb = values + (size_t)b * T_SZ * D_DIM;
    int t0 = tc * 128;
#pragma unroll 2
    for (int t = t0; t < t0 + 128; ++t) {
        float wt = w[(size_t)b * T_SZ + t];
        f32x4 v = *reinterpret_cast<const f32x4*>(vb + (size_t)t * D_DIM + d4 * 4);
        acc += wt * v;
    }
    float* o = out + (size_t)b * D_DIM + d4 * 4;
    atomicAdd(o + 0, acc.x);
    atomicAdd(o + 1, acc.y);
    atomicAdd(o + 2, acc.z);
    atomicAdd(o + 3, acc.w);
}

extern "C" void kernel_launch(void* const* d_in, const int* in_sizes, int n_in,
                              void* d_out, int out_size, void* d_ws, size_t ws_size,
                              hipStream_t stream) {
    (void)in_sizes; (void)n_in; (void)out_size; (void)ws_size;
    const float* query  = (const float*)d_in[0];
    const float* values = (const float*)d_in[1];
    const float* W1     = (const float*)d_in[2];
    const float* b1     = (const float*)d_in[3];
    const float* W2     = (const float*)d_in[4];
    const float* b2     = (const float*)d_in[5];
    const float* Wv     = (const float*)d_in[6];
    // d_in[7] = bv: softmax is shift-invariant and scores are not an output -> unused.

    float* out  = (float*)d_out;             // [B,D] context
    float* wout = out + B_SZ * D_DIM;        // [B,T] attention weights

    char* ws = (char*)d_ws;
    float* scores = (float*)ws;                                   // 65536 f32 (256 KB)
    float* qpb = (float*)(ws + 65536 * 4);                        // 32768 f32 (128 KB)
    unsigned short* W2t = (unsigned short*)(ws + 65536 * 4 + 32768 * 4);  // 1M bf16 (2 MB)

    hipMemsetAsync(scores, 0, 65536 * 4, stream);
    hipMemsetAsync(out, 0, B_SZ * D_DIM * 4, stream);

    w2_transpose<<<dim3(32, 32), dim3(32, 8), 0, stream>>>(W2, W2t);
    qproj<<<dim3(32, 4), 256, 0, stream>>>(query, W1, b1, b2, qpb);
    score_gemm<<<dim3((B_SZ * T_SZ) / BM, U_DIM / BN), 256, 0, stream>>>(values, W2t, qpb, Wv, scores);
    softmax_k<<<B_SZ, 256, 0, stream>>>(scores, wout);
    context_k<<<dim3(B_SZ, 16), 256, 0, stream>>>(values, wout, out);
}

// Round 2
// 474.565 us; speedup vs baseline: 1.0255x; 1.0255x over previous
//
#include <hip/hip_runtime.h>
#include <hip/hip_bf16.h>

#define D_DIM 1024
#define U_DIM 1024
#define B_SZ  32
#define T_SZ  2048

typedef __bf16 bf16x8 __attribute__((ext_vector_type(8)));
typedef float f32x4 __attribute__((ext_vector_type(4)));
typedef unsigned short ushort8 __attribute__((ext_vector_type(8)));
typedef unsigned short ushort4_t __attribute__((ext_vector_type(4)));

__device__ __forceinline__ unsigned short f2bf(float f) {
    union { float f; unsigned u; } v;
    v.f = f;
    unsigned r = v.u + 0x7fffu + ((v.u >> 16) & 1u);  // RNE
    return (unsigned short)(r >> 16);
}

// ---------------- K0: values fp32 -> bf16 (memory-bound pass) ----------------
__global__ __launch_bounds__(256) void vconv(const float* __restrict__ v,
                                             unsigned short* __restrict__ o) {
    const size_t N = (size_t)B_SZ * T_SZ * D_DIM;
    size_t i = ((size_t)blockIdx.x * 256 + threadIdx.x) * 8;
    const size_t stride = (size_t)gridDim.x * 256 * 8;
    for (; i < N; i += stride) {
        f32x4 a = *reinterpret_cast<const f32x4*>(v + i);
        f32x4 b = *reinterpret_cast<const f32x4*>(v + i + 4);
        ushort8 h;
        h[0] = f2bf(a.x); h[1] = f2bf(a.y); h[2] = f2bf(a.z); h[3] = f2bf(a.w);
        h[4] = f2bf(b.x); h[5] = f2bf(b.y); h[6] = f2bf(b.z); h[7] = f2bf(b.w);
        *reinterpret_cast<ushort8*>(o + i) = h;
    }
}

// ---------------- K1: W2 [D,U] fp32 -> W2t [U,D] bf16 ----------------
__global__ __launch_bounds__(256) void w2_transpose(const float* __restrict__ W2,
                                                    unsigned short* __restrict__ W2t) {
    __shared__ float tile[32][33];
    int d0 = blockIdx.x * 32, u0 = blockIdx.y * 32;
    int tx = threadIdx.x, ty = threadIdx.y;  // 32 x 8
#pragma unroll
    for (int i = 0; i < 4; i++)
        tile[ty + 8 * i][tx] = W2[(size_t)(d0 + ty + 8 * i) * U_DIM + u0 + tx];
    __syncthreads();
#pragma unroll
    for (int i = 0; i < 4; i++)
        W2t[(size_t)(u0 + ty + 8 * i) * D_DIM + d0 + tx] = f2bf(tile[tx][ty + 8 * i]);
}

// ---------------- K2: qpb[b,u] = query@W1 + b1 + b2 (fp32) ----------------
__global__ __launch_bounds__(256) void qproj(const float* __restrict__ query,
                                             const float* __restrict__ W1,
                                             const float* __restrict__ b1,
                                             const float* __restrict__ b2,
                                             float* __restrict__ qpb) {
    int b = blockIdx.x;
    int u = blockIdx.y * 256 + threadIdx.x;
    float acc = b1[u] + b2[u];
    const float* q = query + (size_t)b * D_DIM;
#pragma unroll 4
    for (int d = 0; d < D_DIM; d++)
        acc += q[d] * W1[(size_t)d * U_DIM + u];
    qpb[(size_t)b * U_DIM + u] = acc;
}

// ---------------- K3 (primary): fused score GEMM, bf16 A via global_load_lds ----------------
// Each block: 128 rows (t), loops all 8 u-tiles of 128; full K per u-tile;
// per-u-tile tanh epilogue accumulates into registers; single direct store.
#define BM 128
#define BN 128
#define BK 32

__global__ __launch_bounds__(256) void score_gemm_dma(const unsigned short* __restrict__ vbf,
                                                      const unsigned short* __restrict__ W2t,
                                                      const float* __restrict__ qpb,
                                                      const float* __restrict__ Wv,
                                                      float* __restrict__ scores) {
    __shared__ unsigned short Al[BM * BK];  // 8 KB, linear [row][k]
    __shared__ unsigned short Bl[BN * BK];  // 8 KB, linear [u][k]
    const int tid = threadIdx.x;
    const int wave = tid >> 6, lane = tid & 63;
    const int row0 = blockIdx.x * BM;
    const int b = row0 >> 11;  // row0 / T_SZ
    const int lr = lane & 15, lk = lane >> 4;
    const int wt0 = wave * 32;  // each wave owns 32 rows x all 128 u-cols

    // staging geometry: chunk cj = wave*2+j covers rows cj*16..+16 (1 KB each),
    // lane l -> row cj*16 + (l>>2), col (l&3)*8 (16B contiguous in global)
    const int srow = wave * 32 + (lane >> 2);
    const int scol = (lane & 3) * 8;

    float s_acc[2][4] = {{0.f, 0.f, 0.f, 0.f}, {0.f, 0.f, 0.f, 0.f}};

    for (int ut = 0; ut < 8; ++ut) {
        const int u0 = ut * BN;
        f32x4 acc[2][8];
#pragma unroll
        for (int m = 0; m < 2; m++)
#pragma unroll
            for (int n = 0; n < 8; n++) acc[m][n] = (f32x4){0.f, 0.f, 0.f, 0.f};

        for (int k0 = 0; k0 < D_DIM; k0 += BK) {
#pragma unroll
            for (int j = 0; j < 2; j++) {
                const unsigned short* ga =
                    vbf + (size_t)(row0 + srow + j * 16) * D_DIM + k0 + scol;
                auto la = (__attribute__((address_space(3))) unsigned short*)&Al[(wave * 2 + j) * 512];
                __builtin_amdgcn_global_load_lds(
                    (const __attribute__((address_space(1))) void*)ga,
                    (__attribute__((address_space(3))) void*)la, 16, 0, 0);
            }
#pragma unroll
            for (int j = 0; j < 2; j++) {
                const unsigned short* gb =
                    W2t + (size_t)(u0 + srow + j * 16) * D_DIM + k0 + scol;
                auto lb = (__attribute__((address_space(3))) unsigned short*)&Bl[(wave * 2 + j) * 512];
                __builtin_amdgcn_global_load_lds(
                    (const __attribute__((address_space(1))) void*)gb,
                    (__attribute__((address_space(3))) void*)lb, 16, 0, 0);
            }
            __syncthreads();  // drains vmcnt before barrier (compiler-enforced)
            bf16x8 af[2], bfv[8];
#pragma unroll
            for (int m = 0; m < 2; m++)
                af[m] = *reinterpret_cast<const bf16x8*>(&Al[(wt0 + m * 16 + lr) * BK + lk * 8]);
#pragma unroll
            for (int n = 0; n < 8; n++)
                bfv[n] = *reinterpret_cast<const bf16x8*>(&Bl[(n * 16 + lr) * BK + lk * 8]);
#pragma unroll
            for (int m = 0; m < 2; m++)
#pragma unroll
                for (int n = 0; n < 8; n++)
                    acc[m][n] = __builtin_amdgcn_mfma_f32_16x16x32_bf16(af[m], bfv[n], acc[m][n], 0, 0, 0);
            __syncthreads();
        }

        // per-u-tile epilogue: x = vproj + qproj; s += tanh(x)*Wv[u]
#pragma unroll
        for (int n = 0; n < 8; n++) {
            int un = u0 + n * 16 + lr;
            float qv = qpb[(size_t)b * U_DIM + un];
            float wv = Wv[un];
#pragma unroll
            for (int m = 0; m < 2; m++)
#pragma unroll
                for (int r = 0; r < 4; r++) {
                    float x = acc[m][n][r] + qv;
                    float e = __expf(2.0f * x);
                    s_acc[m][r] += (1.0f - 2.0f / (e + 1.0f)) * wv;
                }
        }
    }

    // reduce over the 16 lr-lanes; row = row0 + wt0 + m*16 + lk*4 + r
#pragma unroll
    for (int off = 1; off < 16; off <<= 1)
#pragma unroll
        for (int m = 0; m < 2; m++)
#pragma unroll
            for (int r = 0; r < 4; r++) s_acc[m][r] += __shfl_xor(s_acc[m][r], off);
    if (lr == 0) {
#pragma unroll
        for (int m = 0; m < 2; m++) {
            int trow = row0 + wt0 + m * 16 + lk * 4;
#pragma unroll
            for (int r = 0; r < 4; r++) scores[trow + r] = s_acc[m][r];
        }
    }
}

// ---------------- K3 (fallback, ws too small): round-1 kernel ----------------
#define LDST 40

__global__ __launch_bounds__(256) void score_gemm(const float* __restrict__ values,
                                                  const unsigned short* __restrict__ W2t,
                                                  const float* __restrict__ qpb,
                                                  const float* __restrict__ Wv,
                                                  float* __restrict__ scores) {
    __shared__ unsigned short Al[BM * LDST];
    __shared__ unsigned short Bl[BN * LDST];
    const int tid = threadIdx.x;
    const int row0 = blockIdx.x * BM;
    const int u0 = blockIdx.y * BN;

    f32x4 areg[4];
    ushort8 breg[2];

    auto loadA = [&](int k0) {
#pragma unroll
        for (int j = 0; j < 4; j++) {
            int idx = tid + j * 256;
            int r = idx >> 3, c = idx & 7;
            areg[j] = *reinterpret_cast<const f32x4*>(values + (size_t)(row0 + r) * D_DIM + k0 + c * 4);
        }
    };
    auto loadB = [&](int k0) {
#pragma unroll
        for (int j = 0; j < 2; j++) {
            int idx = tid + j * 256;
            int r = idx >> 2, s = idx & 3;
            breg[j] = *reinterpret_cast<const ushort8*>(W2t + (size_t)(u0 + r) * D_DIM + k0 + s * 8);
        }
    };

    f32x4 acc[4][4] = {};
    const int lane = tid & 63, wave = tid >> 6;
    const int wt0 = (wave >> 1) * 64, wu0 = (wave & 1) * 64;
    const int lr = lane & 15, lk = lane >> 4;

    loadA(0);
    loadB(0);
    for (int k0 = 0; k0 < D_DIM; k0 += BK) {
        __syncthreads();
#pragma unroll
        for (int j = 0; j < 4; j++) {
            int idx = tid + j * 256;
            int r = idx >> 3, c = idx & 7;
            ushort4_t h;
            h.x = f2bf(areg[j].x);
            h.y = f2bf(areg[j].y);
            h.z = f2bf(areg[j].z);
            h.w = f2bf(areg[j].w);
            *reinterpret_cast<ushort4_t*>(&Al[r * LDST + c * 4]) = h;
        }
#pragma unroll
        for (int j = 0; j < 2; j++) {
            int idx = tid + j * 256;
            int r = idx >> 2, s = idx & 3;
            *reinterpret_cast<ushort8*>(&Bl[r * LDST + s * 8]) = breg[j];
        }
        __syncthreads();
        if (k0 + BK < D_DIM) {
            loadA(k0 + BK);
            loadB(k0 + BK);
        }
        bf16x8 af[4], bfr[4];
#pragma unroll
        for (int m = 0; m < 4; m++)
            af[m] = *reinterpret_cast<const bf16x8*>(&Al[(wt0 + m * 16 + lr) * LDST + lk * 8]);
#pragma unroll
        for (int n = 0; n < 4; n++)
            bfr[n] = *reinterpret_cast<const bf16x8*>(&Bl[(wu0 + n * 16 + lr) * LDST + lk * 8]);
#pragma unroll
        for (int m = 0; m < 4; m++)
#pragma unroll
            for (int n = 0; n < 4; n++)
                acc[m][n] = __builtin_amdgcn_mfma_f32_16x16x32_bf16(af[m], bfr[n], acc[m][n], 0, 0, 0);
    }

    const int b = row0 >> 11;
    float qv[4], wvv[4];
#pragma unroll
    for (int n = 0; n < 4; n++) {
        int un = u0 + wu0 + n * 16 + lr;
        qv[n] = qpb[(size_t)b * U_DIM + un];
        wvv[n] = Wv[un];
    }
#pragma unroll
    for (int m = 0; m < 4; m++) {
        float s[4] = {0.f, 0.f, 0.f, 0.f};
#pragma unroll
        for (int n = 0; n < 4; n++) {
#pragma unroll
            for (int r = 0; r < 4; r++) {
                float x = acc[m][n][r] + qv[n];
                float e = __expf(2.0f * x);
                float th = 1.0f - 2.0f / (e + 1.0f);
                s[r] += th * wvv[n];
            }
        }
#pragma unroll
        for (int off = 1; off < 16; off <<= 1) {
#pragma unroll
            for (int r = 0; r < 4; r++) s[r] += __shfl_xor(s[r], off);
        }
        if (lr == 0) {
            int trow = row0 + wt0 + m * 16 + lk * 4;
#pragma unroll
            for (int r = 0; r < 4; r++) atomicAdd(&scores[trow + r], s[r]);
        }
    }
}

// ---------------- K4: softmax over T per batch ----------------
__global__ __launch_bounds__(256) void softmax_k(const float* __restrict__ scores,
                                                 float* __restrict__ wout) {
    int b = blockIdx.x, tid = threadIdx.x;
    int lane = tid & 63, wave = tid >> 6;
    __shared__ float redm[4], reds[4];
    float v[8];
    float mx = -3.4e38f;
#pragma unroll
    for (int i = 0; i < 8; i++) {
        v[i] = scores[(size_t)b * T_SZ + tid + i * 256];
        mx = fmaxf(mx, v[i]);
    }
#pragma unroll
    for (int off = 1; off < 64; off <<= 1) mx = fmaxf(mx, __shfl_xor(mx, off));
    if (lane == 0) redm[wave] = mx;
    __syncthreads();
    mx = fmaxf(fmaxf(redm[0], redm[1]), fmaxf(redm[2], redm[3]));
    float sum = 0.f;
#pragma unroll
    for (int i = 0; i < 8; i++) {
        v[i] = __expf(v[i] - mx);
        sum += v[i];
    }
#pragma unroll
    for (int off = 1; off < 64; off <<= 1) sum += __shfl_xor(sum, off);
    if (lane == 0) reds[wave] = sum;
    __syncthreads();
    sum = reds[0] + reds[1] + reds[2] + reds[3];
    float inv = 1.0f / sum;
#pragma unroll
    for (int i = 0; i < 8; i++) wout[(size_t)b * T_SZ + tid + i * 256] = v[i] * inv;
}

// ---------------- K5: context[b,d] = sum_t w[b,t] * values[b,t,d] ----------------
__global__ __launch_bounds__(256) void context_k(const float* __restrict__ values,
                                                 const float* __restrict__ w,
                                                 float* __restrict__ out) {
    int b = blockIdx.x, tc = blockIdx.y;
    int d4 = threadIdx.x;
    f32x4 acc = {0.f, 0.f, 0.f, 0.f};
    const float* vb = values + (size_t)b * T_SZ * D_DIM;
    int t0 = tc * 128;
#pragma unroll 2
    for (int t = t0; t < t0 + 128; ++t) {
        float wt = w[(size_t)b * T_SZ + t];
        f32x4 v = *reinterpret_cast<const f32x4*>(vb + (size_t)t * D_DIM + d4 * 4);
        acc += wt * v;
    }
    float* o = out + (size_t)b * D_DIM + d4 * 4;
    atomicAdd(o + 0, acc.x);
    atomicAdd(o + 1, acc.y);
    atomicAdd(o + 2, acc.z);
    atomicAdd(o + 3, acc.w);
}

extern "C" void kernel_launch(void* const* d_in, const int* in_sizes, int n_in,
                              void* d_out, int out_size, void* d_ws, size_t ws_size,
                              hipStream_t stream) {
    (void)in_sizes; (void)n_in; (void)out_size;
    const float* query  = (const float*)d_in[0];
    const float* values = (const float*)d_in[1];
    const float* W1     = (const float*)d_in[2];
    const float* b1     = (const float*)d_in[3];
    const float* W2     = (const float*)d_in[4];
    const float* b2     = (const float*)d_in[5];
    const float* Wv     = (const float*)d_in[6];
    // d_in[7] = bv: softmax is shift-invariant; scores aren't an output -> unused.

    float* out  = (float*)d_out;             // [B,D] context
    float* wout = out + B_SZ * D_DIM;        // [B,T] attention weights

    const size_t VN = (size_t)B_SZ * T_SZ * D_DIM;  // 64M elems
    const size_t need = VN * 2 + 65536 * 4 + 32768 * 4 + (size_t)U_DIM * D_DIM * 2;

    char* ws = (char*)d_ws;

    hipMemsetAsync(out, 0, B_SZ * D_DIM * 4, stream);

    if (ws_size >= need) {
        // primary path: bf16-preconverted values + global_load_lds GEMM
        unsigned short* vbf = (unsigned short*)ws;                     // 128 MB
        float* scores = (float*)(ws + VN * 2);                         // 256 KB
        float* qpb = scores + 65536;                                   // 128 KB
        unsigned short* W2t = (unsigned short*)(qpb + 32768);          // 2 MB

        vconv<<<2048, 256, 0, stream>>>(values, vbf);
        w2_transpose<<<dim3(32, 32), dim3(32, 8), 0, stream>>>(W2, W2t);
        qproj<<<dim3(32, 4), 256, 0, stream>>>(query, W1, b1, b2, qpb);
        score_gemm_dma<<<512, 256, 0, stream>>>(vbf, W2t, qpb, Wv, scores);
        softmax_k<<<B_SZ, 256, 0, stream>>>(scores, wout);
        context_k<<<dim3(B_SZ, 16), 256, 0, stream>>>(values, wout, out);
    } else {
        // fallback: round-1 proven path
        float* scores = (float*)ws;                                    // 256 KB
        float* qpb = (float*)(ws + 65536 * 4);                         // 128 KB
        unsigned short* W2t = (unsigned short*)(ws + 65536 * 4 + 32768 * 4);  // 2 MB

        hipMemsetAsync(scores, 0, 65536 * 4, stream);
        w2_transpose<<<dim3(32, 32), dim3(32, 8), 0, stream>>>(W2, W2t);
        qproj<<<dim3(32, 4), 256, 0, stream>>>(query, W1, b1, b2, qpb);
        score_gemm<<<dim3((B_SZ * T_SZ) / BM, U_DIM / BN), 256, 0, stream>>>(values, W2t, qpb, Wv, scores);
        softmax_k<<<B_SZ, 256, 0, stream>>>(scores, wout);
        context_k<<<dim3(B_SZ, 16), 256, 0, stream>>>(values, wout, out);
    }
}

// Round 3
// 433.046 us; speedup vs baseline: 1.1238x; 1.0959x over previous
//
#include <hip/hip_runtime.h>
#include <hip/hip_bf16.h>

#define D_DIM 1024
#define U_DIM 1024
#define B_SZ  32
#define T_SZ  2048

typedef __bf16 bf16x8 __attribute__((ext_vector_type(8)));
typedef float f32x4 __attribute__((ext_vector_type(4)));
typedef unsigned short ushort8 __attribute__((ext_vector_type(8)));

#define AS1 __attribute__((address_space(1)))
#define AS3 __attribute__((address_space(3)))

__device__ __forceinline__ unsigned short f2bf(float f) {
    union { float f; unsigned u; } v;
    v.f = f;
    unsigned r = v.u + 0x7fffu + ((v.u >> 16) & 1u);  // RNE
    return (unsigned short)(r >> 16);
}

// XOR-swizzle: spreads 16B slots (bits 4-5) by row bits (bits 7-8).
// Involution; applied to both stage-source addressing and ds_read addressing.
__device__ __forceinline__ int swz(int a) { return a ^ (((a >> 7) & 3) << 4); }

// ---------------- K1 (fused prep): vconv + W2 transpose + qproj + zero(out) ----------------
__global__ __launch_bounds__(256) void prep(const float* __restrict__ values,
                                            unsigned short* __restrict__ vbf,
                                            const float* __restrict__ W2,
                                            unsigned short* __restrict__ W2t,
                                            const float* __restrict__ query,
                                            const float* __restrict__ W1,
                                            const float* __restrict__ b1,
                                            const float* __restrict__ b2,
                                            float* __restrict__ qpb,
                                            float* __restrict__ out) {
    __shared__ float tile[32][33];
    const int v = blockIdx.x;
    const int tid = threadIdx.x;
    if (v < 2048) {
        // values fp32 -> bf16, plain row-major
        const size_t N = (size_t)B_SZ * T_SZ * D_DIM;
        size_t i = ((size_t)v * 256 + tid) * 8;
        const size_t stride = (size_t)2048 * 256 * 8;
        for (; i < N; i += stride) {
            f32x4 a = *reinterpret_cast<const f32x4*>(values + i);
            f32x4 b = *reinterpret_cast<const f32x4*>(values + i + 4);
            ushort8 h;
            h[0] = f2bf(a.x); h[1] = f2bf(a.y); h[2] = f2bf(a.z); h[3] = f2bf(a.w);
            h[4] = f2bf(b.x); h[5] = f2bf(b.y); h[6] = f2bf(b.z); h[7] = f2bf(b.w);
            *reinterpret_cast<ushort8*>(vbf + i) = h;
        }
    } else if (v < 3072) {
        // W2 [D,U] -> W2t [U,D] bf16
        const int q = v - 2048;
        const int d0 = (q & 31) * 32, u0 = (q >> 5) * 32;
        const int tx = tid & 31, ty = tid >> 5;  // 32 x 8
#pragma unroll
        for (int i = 0; i < 4; i++)
            tile[ty + 8 * i][tx] = W2[(size_t)(d0 + ty + 8 * i) * U_DIM + u0 + tx];
        __syncthreads();
#pragma unroll
        for (int i = 0; i < 4; i++)
            W2t[(size_t)(u0 + ty + 8 * i) * D_DIM + d0 + tx] = f2bf(tile[tx][ty + 8 * i]);
    } else if (v < 3200) {
        // qpb[b,u] = query@W1 + b1 + b2 (fp32)
        const int q = v - 3072;
        const int b = q >> 2;
        const int u = (q & 3) * 256 + tid;
        float acc = b1[u] + b2[u];
        const float* qr = query + (size_t)b * D_DIM;
#pragma unroll 4
        for (int d = 0; d < D_DIM; d++)
            acc += qr[d] * W1[(size_t)d * U_DIM + u];
        qpb[(size_t)b * U_DIM + u] = acc;
    } else {
        // zero context output (context_k accumulates with atomics)
        const int q = v - 3200;  // 16 blocks * 256 thr * 8 = 32768
        size_t i = ((size_t)q * 256 + tid) * 8;
        *reinterpret_cast<f32x4*>(out + i) = (f32x4){0.f, 0.f, 0.f, 0.f};
        *reinterpret_cast<f32x4*>(out + i + 4) = (f32x4){0.f, 0.f, 0.f, 0.f};
    }
}

// ---------------- K2: fused score GEMM, depth-2 prefetch ring + counted vmcnt ----------------
// Block: 128 rows x all 1024 u (2 passes of BN=512), BK=32, 8 waves (2m x 4n),
// wave tile 64 rows x 128 u, 16x16x32 bf16 MFMA, acc[4][8].
// LDS: 3 ring buffers x (A 8KB + B 32KB) = 120 KB + 8 KB qpb/Wv cache = 128 KB.
__global__ __launch_bounds__(512, 2) void score_gemm3(const unsigned short* __restrict__ vbf,
                                                      const unsigned short* __restrict__ W2t,
                                                      const float* __restrict__ qpb,
                                                      const float* __restrict__ Wv,
                                                      float* __restrict__ scores) {
    __shared__ char smem[131072];
    const int tid = threadIdx.x, wave = tid >> 6, lane = tid & 63;
    const int lr = lane & 15, lk = lane >> 4;
    const int wm = wave >> 2, wn = wave & 3;
    const int row0 = blockIdx.x * 128;
    const int b = row0 >> 11;  // row0 / T_SZ

    // prologue: cache qpb row + Wv in LDS so epilogues issue no vmem (vmcnt stays exact)
    float* qW = (float*)(smem + 122880);  // 1024 f32
    float* wV = (float*)(smem + 126976);  // 1024 f32
    qW[tid] = qpb[(size_t)b * U_DIM + tid];
    qW[tid + 512] = qpb[(size_t)b * U_DIM + tid + 512];
    wV[tid] = Wv[tid];
    wV[tid + 512] = Wv[tid + 512];

    // stage-source offsets (pre-swizzled per-lane GLOBAL addresses; LDS dest stays linear)
    const int aA = tid * 16;  // my A chunk's LDS byte offset within the A region
    const int sA = swz(aA);
    const size_t gAoff = (size_t)(row0 + (sA >> 6)) * D_DIM + ((sA & 63) >> 1);
    size_t gBoff[4];
#pragma unroll
    for (int j = 0; j < 4; j++) {
        int aB = (wave * 4 + j) * 1024 + lane * 16;
        int sB = swz(aB);
        gBoff[j] = (size_t)(sB >> 6) * D_DIM + ((sB & 63) >> 1);
    }
    // ds_read offsets (swizzled)
    int offA[4], offB[8];
#pragma unroll
    for (int m = 0; m < 4; m++) offA[m] = swz((wm * 64 + m * 16 + lr) * 64 + lk * 16);
#pragma unroll
    for (int n = 0; n < 8; n++) offB[n] = 8192 + swz((wn * 128 + n * 16 + lr) * 64 + lk * 16);

    auto stage = [&](int tt, int bo) {
        const int ut = tt >> 5;
        const int ks = (tt & 31) << 5;
        const unsigned short* ga = vbf + gAoff + ks;
        __builtin_amdgcn_global_load_lds((const AS1 void*)ga,
                                         (AS3 void*)(smem + bo + wave * 1024), 16, 0, 0);
#pragma unroll
        for (int j = 0; j < 4; j++) {
            const unsigned short* gb = W2t + ((size_t)ut << 19) + gBoff[j] + ks;
            __builtin_amdgcn_global_load_lds((const AS1 void*)gb,
                                             (AS3 void*)(smem + bo + 8192 + (wave * 4 + j) * 1024),
                                             16, 0, 0);
        }
    };

    stage(0, 0);
    stage(1, 40960);

    f32x4 acc[4][8];
    float s_acc[4][4] = {{0.f, 0.f, 0.f, 0.f}, {0.f, 0.f, 0.f, 0.f},
                         {0.f, 0.f, 0.f, 0.f}, {0.f, 0.f, 0.f, 0.f}};
    int bo_comp = 0;

    for (int t = 0; t < 64; ++t) {
        if (t < 62) {
            int bo_stage = bo_comp + 81920;
            if (bo_stage >= 122880) bo_stage -= 122880;
            stage(t + 2, bo_stage);
            // 15 in flight after issue; retire oldest 5 (= stage(t)) only
            asm volatile("s_waitcnt vmcnt(10)" ::: "memory");
        } else if (t == 62) {
            asm volatile("s_waitcnt vmcnt(5)" ::: "memory");
        } else {
            asm volatile("s_waitcnt vmcnt(0)" ::: "memory");
        }
        __builtin_amdgcn_sched_barrier(0);
        __builtin_amdgcn_s_barrier();
        __builtin_amdgcn_sched_barrier(0);

        if ((t & 31) == 0) {
#pragma unroll
            for (int m = 0; m < 4; m++)
#pragma unroll
                for (int n = 0; n < 8; n++) acc[m][n] = (f32x4){0.f, 0.f, 0.f, 0.f};
        }

        bf16x8 af[4], bfv[8];
#pragma unroll
        for (int m = 0; m < 4; m++)
            af[m] = *reinterpret_cast<const bf16x8*>(smem + bo_comp + offA[m]);
#pragma unroll
        for (int n = 0; n < 8; n++)
            bfv[n] = *reinterpret_cast<const bf16x8*>(smem + bo_comp + offB[n]);
#pragma unroll
        for (int m = 0; m < 4; m++)
#pragma unroll
            for (int n = 0; n < 8; n++)
                acc[m][n] = __builtin_amdgcn_mfma_f32_16x16x32_bf16(af[m], bfv[n], acc[m][n], 0, 0, 0);

        if ((t & 31) == 31) {  // end of a BN=512 u-pass: tanh epilogue into s_acc
            const int ut = t >> 5;
#pragma unroll
            for (int n = 0; n < 8; n++) {
                const int un = ut * 512 + wn * 128 + n * 16 + lr;
                const float qv = qW[un];
                const float wv = wV[un];
#pragma unroll
                for (int m = 0; m < 4; m++)
#pragma unroll
                    for (int r = 0; r < 4; r++) {
                        float x = acc[m][n][r] + qv;
                        float e = __expf(2.0f * x);
                        s_acc[m][r] += (1.0f - 2.0f / (e + 1.0f)) * wv;
                    }
            }
        }
        __builtin_amdgcn_sched_barrier(0);
        __builtin_amdgcn_s_barrier();
        __builtin_amdgcn_sched_barrier(0);
        bo_comp += 40960;
        if (bo_comp >= 122880) bo_comp = 0;
    }

    // reduce over the 16 lr-lanes
#pragma unroll
    for (int off = 1; off < 16; off <<= 1)
#pragma unroll
        for (int m = 0; m < 4; m++)
#pragma unroll
            for (int r = 0; r < 4; r++) s_acc[m][r] += __shfl_xor(s_acc[m][r], off);

    // cross-wave (4 wn) reduce via LDS (buffers are dead now), then direct store
    float* red = (float*)smem;  // [4][128]
    if (lr == 0) {
#pragma unroll
        for (int m = 0; m < 4; m++)
#pragma unroll
            for (int r = 0; r < 4; r++)
                red[wn * 128 + wm * 64 + m * 16 + lk * 4 + r] = s_acc[m][r];
    }
    __syncthreads();
    if (tid < 128) {
        float s = red[tid] + red[128 + tid] + red[256 + tid] + red[384 + tid];
        scores[row0 + tid] = s;
    }
}

// ---------------- K3: softmax over T per batch ----------------
__global__ __launch_bounds__(256) void softmax_k(const float* __restrict__ scores,
                                                 float* __restrict__ wout) {
    int b = blockIdx.x, tid = threadIdx.x;
    int lane = tid & 63, wave = tid >> 6;
    __shared__ float redm[4], reds[4];
    float v[8];
    float mx = -3.4e38f;
#pragma unroll
    for (int i = 0; i < 8; i++) {
        v[i] = scores[(size_t)b * T_SZ + tid + i * 256];
        mx = fmaxf(mx, v[i]);
    }
#pragma unroll
    for (int off = 1; off < 64; off <<= 1) mx = fmaxf(mx, __shfl_xor(mx, off));
    if (lane == 0) redm[wave] = mx;
    __syncthreads();
    mx = fmaxf(fmaxf(redm[0], redm[1]), fmaxf(redm[2], redm[3]));
    float sum = 0.f;
#pragma unroll
    for (int i = 0; i < 8; i++) {
        v[i] = __expf(v[i] - mx);
        sum += v[i];
    }
#pragma unroll
    for (int off = 1; off < 64; off <<= 1) sum += __shfl_xor(sum, off);
    if (lane == 0) reds[wave] = sum;
    __syncthreads();
    sum = reds[0] + reds[1] + reds[2] + reds[3];
    float inv = 1.0f / sum;
#pragma unroll
    for (int i = 0; i < 8; i++) wout[(size_t)b * T_SZ + tid + i * 256] = v[i] * inv;
}

// ---------------- K4: context[b,d] = sum_t w[b,t] * values[b,t,d] ----------------
__global__ __launch_bounds__(256) void context_k(const float* __restrict__ values,
                                                 const float* __restrict__ w,
                                                 float* __restrict__ out) {
    int b = blockIdx.x, tc = blockIdx.y;
    int d4 = threadIdx.x;
    f32x4 acc = {0.f, 0.f, 0.f, 0.f};
    const float* vb = values + (size_t)b * T_SZ * D_DIM;
    int t0 = tc * 64;
#pragma unroll 2
    for (int t = t0; t < t0 + 64; ++t) {
        float wt = w[(size_t)b * T_SZ + t];
        f32x4 v = *reinterpret_cast<const f32x4*>(vb + (size_t)t * D_DIM + d4 * 4);
        acc += wt * v;
    }
    float* o = out + (size_t)b * D_DIM + d4 * 4;
    atomicAdd(o + 0, acc.x);
    atomicAdd(o + 1, acc.y);
    atomicAdd(o + 2, acc.z);
    atomicAdd(o + 3, acc.w);
}

extern "C" void kernel_launch(void* const* d_in, const int* in_sizes, int n_in,
                              void* d_out, int out_size, void* d_ws, size_t ws_size,
                              hipStream_t stream) {
    (void)in_sizes; (void)n_in; (void)out_size; (void)ws_size;
    const float* query  = (const float*)d_in[0];
    const float* values = (const float*)d_in[1];
    const float* W1     = (const float*)d_in[2];
    const float* b1     = (const float*)d_in[3];
    const float* W2     = (const float*)d_in[4];
    const float* b2     = (const float*)d_in[5];
    const float* Wv     = (const float*)d_in[6];
    // d_in[7] = bv: softmax is shift-invariant; scores aren't an output -> unused.

    float* out  = (float*)d_out;             // [B,D] context
    float* wout = out + B_SZ * D_DIM;        // [B,T] attention weights

    const size_t VN = (size_t)B_SZ * T_SZ * D_DIM;  // 64M elems
    char* ws = (char*)d_ws;
    unsigned short* vbf = (unsigned short*)ws;                     // 128 MB
    float* scores = (float*)(ws + VN * 2);                         // 256 KB
    float* qpb = scores + 65536;                                   // 128 KB
    unsigned short* W2t = (unsigned short*)(qpb + 32768);          // 2 MB

    prep<<<3216, 256, 0, stream>>>(values, vbf, W2, W2t, query, W1, b1, b2, qpb, out);
    score_gemm3<<<512, 512, 0, stream>>>(vbf, W2t, qpb, Wv, scores);
    softmax_k<<<B_SZ, 256, 0, stream>>>(scores, wout);
    context_k<<<dim3(B_SZ, 32), 256, 0, stream>>>(values, wout, out);
}

// Round 4
// 331.899 us; speedup vs baseline: 1.4663x; 1.3048x over previous
//
#include <hip/hip_runtime.h>
#include <hip/hip_bf16.h>

#define D_DIM 1024
#define U_DIM 1024
#define B_SZ  32
#define T_SZ  2048

typedef __bf16 bf16x8 __attribute__((ext_vector_type(8)));
typedef float f32x4 __attribute__((ext_vector_type(4)));
typedef unsigned short ushort8 __attribute__((ext_vector_type(8)));

#define AS1 __attribute__((address_space(1)))
#define AS3 __attribute__((address_space(3)))

__device__ __forceinline__ unsigned short f2bf(float f) {
    union { float f; unsigned u; } v;
    v.f = f;
    unsigned r = v.u + 0x7fffu + ((v.u >> 16) & 1u);  // RNE
    return (unsigned short)(r >> 16);
}

// XOR-swizzle (involution): spreads 16B slots (bits 4-5) by row bits (bits 7-8).
__device__ __forceinline__ int swz(int a) { return a ^ (((a >> 7) & 3) << 4); }

// ---------------- K0: values fp32 -> bf16, 64B/lane, no loop ----------------
__global__ __launch_bounds__(256) void vconv2(const float* __restrict__ v,
                                              unsigned short* __restrict__ o) {
    size_t i = ((size_t)blockIdx.x * 256 + threadIdx.x) * 16;
    f32x4 a0 = *reinterpret_cast<const f32x4*>(v + i);
    f32x4 a1 = *reinterpret_cast<const f32x4*>(v + i + 4);
    f32x4 a2 = *reinterpret_cast<const f32x4*>(v + i + 8);
    f32x4 a3 = *reinterpret_cast<const f32x4*>(v + i + 12);
    ushort8 h0, h1;
    h0[0] = f2bf(a0.x); h0[1] = f2bf(a0.y); h0[2] = f2bf(a0.z); h0[3] = f2bf(a0.w);
    h0[4] = f2bf(a1.x); h0[5] = f2bf(a1.y); h0[6] = f2bf(a1.z); h0[7] = f2bf(a1.w);
    h1[0] = f2bf(a2.x); h1[1] = f2bf(a2.y); h1[2] = f2bf(a2.z); h1[3] = f2bf(a2.w);
    h1[4] = f2bf(a3.x); h1[5] = f2bf(a3.y); h1[6] = f2bf(a3.z); h1[7] = f2bf(a3.w);
    *reinterpret_cast<ushort8*>(o + i) = h0;
    *reinterpret_cast<ushort8*>(o + i + 8) = h1;
}

// ---------------- K1: W2 [D,U] fp32 -> W2t [U,D] bf16 ----------------
__global__ __launch_bounds__(256) void w2_transpose(const float* __restrict__ W2,
                                                    unsigned short* __restrict__ W2t) {
    __shared__ float tile[32][33];
    int d0 = blockIdx.x * 32, u0 = blockIdx.y * 32;
    int tx = threadIdx.x, ty = threadIdx.y;  // 32 x 8
#pragma unroll
    for (int i = 0; i < 4; i++)
        tile[ty + 8 * i][tx] = W2[(size_t)(d0 + ty + 8 * i) * U_DIM + u0 + tx];
    __syncthreads();
#pragma unroll
    for (int i = 0; i < 4; i++)
        W2t[(size_t)(u0 + ty + 8 * i) * D_DIM + d0 + tx] = f2bf(tile[tx][ty + 8 * i]);
}

// ---------------- K2: qpb[b,u] = query@W1 + b1 + b2 (fp32), K split 4-way ----------------
__global__ __launch_bounds__(256) void qproj2(const float* __restrict__ query,
                                              const float* __restrict__ W1,
                                              const float* __restrict__ b1,
                                              const float* __restrict__ b2,
                                              float* __restrict__ qpb) {
    __shared__ float red[4][64];
    const int b = blockIdx.x;
    const int u0 = blockIdx.y * 64;
    const int tid = threadIdx.x;
    const int ul = tid & 63, kq = tid >> 6;
    const int u = u0 + ul;
    float acc = 0.f;
    const float* q = query + (size_t)b * D_DIM;
#pragma unroll 4
    for (int k = kq * 256; k < kq * 256 + 256; k++)
        acc += q[k] * W1[(size_t)k * U_DIM + u];
    red[kq][ul] = acc;
    __syncthreads();
    if (tid < 64) {
        float s = red[0][tid] + red[1][tid] + red[2][tid] + red[3][tid];
        qpb[(size_t)b * U_DIM + u0 + tid] = s + b1[u0 + tid] + b2[u0 + tid];
    }
}

// ---------------- K3: fused score GEMM — 1 barrier/step, 3-buf ring, counted vmcnt ----------------
// Block: 128 rows, 2 passes of BN=512 over u, BK=32, 8 waves (2m x 4n),
// wave tile 64 rows x 128 u, acc[4][8]. LDS: 3 x (A 8KB + B 32KB) = 120 KB.
__global__ __launch_bounds__(512) void score_gemm5(const unsigned short* __restrict__ vbf,
                                                   const unsigned short* __restrict__ W2t,
                                                   const float* __restrict__ qpb,
                                                   const float* __restrict__ Wv,
                                                   float* __restrict__ scores) {
    __shared__ char smem[122880];
    const int tid = threadIdx.x, wave = tid >> 6, lane = tid & 63;
    const int lr = lane & 15, lk = lane >> 4;
    const int wm = wave >> 2, wn = wave & 3;
    const int row0 = blockIdx.x * 128;
    const int b = row0 >> 11;  // row0 / T_SZ

    // prologue: qpb/Wv fragments into registers (static arrays; no in-loop vmem)
    float qv0[8], wv0[8], qv1[8], wv1[8];
#pragma unroll
    for (int n = 0; n < 8; n++) {
        const int un = wn * 128 + n * 16 + lr;
        qv0[n] = qpb[(size_t)b * U_DIM + un];
        wv0[n] = Wv[un];
        qv1[n] = qpb[(size_t)b * U_DIM + 512 + un];
        wv1[n] = Wv[512 + un];
    }

    // stage-source offsets (pre-swizzled per-lane GLOBAL addresses; LDS dest linear)
    const int sA = swz(tid * 16);
    const size_t gAoff = (size_t)(row0 + (sA >> 6)) * D_DIM + ((sA & 63) >> 1);
    size_t gBoff[4];
#pragma unroll
    for (int j = 0; j < 4; j++) {
        int sB = swz((wave * 4 + j) * 1024 + lane * 16);
        gBoff[j] = (size_t)(sB >> 6) * D_DIM + ((sB & 63) >> 1);
    }
    // ds_read offsets (swizzled)
    int offA[4], offB[8];
#pragma unroll
    for (int m = 0; m < 4; m++) offA[m] = swz((wm * 64 + m * 16 + lr) * 64 + lk * 16);
#pragma unroll
    for (int n = 0; n < 8; n++) offB[n] = 8192 + swz((wn * 128 + n * 16 + lr) * 64 + lk * 16);

    auto stage = [&](int tt, int bo) {
        const int ut = tt >> 5;
        const int ks = (tt & 31) << 5;
        __builtin_amdgcn_global_load_lds((const AS1 void*)(vbf + gAoff + ks),
                                         (AS3 void*)(smem + bo + wave * 1024), 16, 0, 0);
#pragma unroll
        for (int j = 0; j < 4; j++) {
            __builtin_amdgcn_global_load_lds(
                (const AS1 void*)(W2t + ((size_t)ut << 19) + gBoff[j] + ks),
                (AS3 void*)(smem + bo + 8192 + (wave * 4 + j) * 1024), 16, 0, 0);
        }
    };

    // drain prologue register loads so in-loop vmcnt counts only stage loads
    asm volatile("s_waitcnt vmcnt(0)" ::: "memory");
    stage(0, 0);
    stage(1, 40960);

    f32x4 acc[4][8];
    float s_acc[4][4] = {{0.f, 0.f, 0.f, 0.f}, {0.f, 0.f, 0.f, 0.f},
                         {0.f, 0.f, 0.f, 0.f}, {0.f, 0.f, 0.f, 0.f}};

#define EPI(QV, WV)                                                          \
    {                                                                        \
        _Pragma("unroll") for (int n = 0; n < 8; n++) {                      \
            const float qv = QV[n], wv = WV[n];                              \
            _Pragma("unroll") for (int m = 0; m < 4; m++)                    \
                _Pragma("unroll") for (int r = 0; r < 4; r++) {              \
                    float x = acc[m][n][r] + qv;                             \
                    float e = __expf(2.0f * x);                              \
                    s_acc[m][r] += (1.0f - 2.0f / (e + 1.0f)) * wv;          \
                }                                                            \
        }                                                                    \
    }

    for (int ut = 0; ut < 2; ++ut) {
#pragma unroll
        for (int m = 0; m < 4; m++)
#pragma unroll
            for (int n = 0; n < 8; n++) acc[m][n] = (f32x4){0.f, 0.f, 0.f, 0.f};

        for (int ks = 0; ks < 32; ++ks) {
            const int t = ut * 32 + ks;
            // retire stage(t); keep stage(t+1) [and soon t+2] in flight
            if (t < 63) asm volatile("s_waitcnt vmcnt(5)" ::: "memory");
            else        asm volatile("s_waitcnt vmcnt(0)" ::: "memory");
            __builtin_amdgcn_s_barrier();

            const int bo = (t % 3) * 40960;
            bf16x8 af[4], bfv[8];
#pragma unroll
            for (int m = 0; m < 4; m++)
                af[m] = *reinterpret_cast<const bf16x8*>(smem + bo + offA[m]);
#pragma unroll
            for (int n = 0; n < 8; n++)
                bfv[n] = *reinterpret_cast<const bf16x8*>(smem + bo + offB[n]);

            if (t < 62) stage(t + 2, ((t + 2) % 3) * 40960);

            __builtin_amdgcn_s_setprio(1);
#pragma unroll
            for (int m = 0; m < 4; m++)
#pragma unroll
                for (int n = 0; n < 8; n++)
                    acc[m][n] = __builtin_amdgcn_mfma_f32_16x16x32_bf16(af[m], bfv[n], acc[m][n], 0, 0, 0);
            __builtin_amdgcn_s_setprio(0);

            // all my ds_reads complete before next barrier -> ring overwrite is race-free
            asm volatile("s_waitcnt lgkmcnt(0)" ::: "memory");
            __builtin_amdgcn_sched_barrier(0);
        }
        if (ut == 0) EPI(qv0, wv0) else EPI(qv1, wv1);
    }
#undef EPI

    // reduce over the 16 lr-lanes
#pragma unroll
    for (int off = 1; off < 16; off <<= 1)
#pragma unroll
        for (int m = 0; m < 4; m++)
#pragma unroll
            for (int r = 0; r < 4; r++) s_acc[m][r] += __shfl_xor(s_acc[m][r], off);

    // cross-wave (4 wn) reduce via LDS, then direct store
    __syncthreads();
    float* red = (float*)smem;  // [4][128]
    if (lr == 0) {
#pragma unroll
        for (int m = 0; m < 4; m++)
#pragma unroll
            for (int r = 0; r < 4; r++)
                red[wn * 128 + wm * 64 + m * 16 + lk * 4 + r] = s_acc[m][r];
    }
    __syncthreads();
    if (tid < 128) {
        float s = red[tid] + red[128 + tid] + red[256 + tid] + red[384 + tid];
        scores[row0 + tid] = s;
    }
}

// ---------------- K4: softmax over T per batch (+ zero context output) ----------------
__global__ __launch_bounds__(256) void softmax_z(const float* __restrict__ scores,
                                                 float* __restrict__ wout,
                                                 float* __restrict__ out) {
    int b = blockIdx.x, tid = threadIdx.x;
    int lane = tid & 63, wave = tid >> 6;
    __shared__ float redm[4], reds[4];
    // zero out[b,:] for context_k's atomics
    *reinterpret_cast<f32x4*>(out + (size_t)b * D_DIM + tid * 4) = (f32x4){0.f, 0.f, 0.f, 0.f};
    float v[8];
    float mx = -3.4e38f;
#pragma unroll
    for (int i = 0; i < 8; i++) {
        v[i] = scores[(size_t)b * T_SZ + tid + i * 256];
        mx = fmaxf(mx, v[i]);
    }
#pragma unroll
    for (int off = 1; off < 64; off <<= 1) mx = fmaxf(mx, __shfl_xor(mx, off));
    if (lane == 0) redm[wave] = mx;
    __syncthreads();
    mx = fmaxf(fmaxf(redm[0], redm[1]), fmaxf(redm[2], redm[3]));
    float sum = 0.f;
#pragma unroll
    for (int i = 0; i < 8; i++) {
        v[i] = __expf(v[i] - mx);
        sum += v[i];
    }
#pragma unroll
    for (int off = 1; off < 64; off <<= 1) sum += __shfl_xor(sum, off);
    if (lane == 0) reds[wave] = sum;
    __syncthreads();
    sum = reds[0] + reds[1] + reds[2] + reds[3];
    float inv = 1.0f / sum;
#pragma unroll
    for (int i = 0; i < 8; i++) wout[(size_t)b * T_SZ + tid + i * 256] = v[i] * inv;
}

// ---------------- K5: context[b,d] = sum_t w[b,t] * values[b,t,d] ----------------
__global__ __launch_bounds__(256) void context_k(const float* __restrict__ values,
                                                 const float* __restrict__ w,
                                                 float* __restrict__ out) {
    int b = blockIdx.x, tc = blockIdx.y;
    int d4 = threadIdx.x;
    f32x4 acc = {0.f, 0.f, 0.f, 0.f};
    const float* vb = values + (size_t)b * T_SZ * D_DIM;
    int t0 = tc * 64;
#pragma unroll 2
    for (int t = t0; t < t0 + 64; ++t) {
        float wt = w[(size_t)b * T_SZ + t];
        f32x4 v = *reinterpret_cast<const f32x4*>(vb + (size_t)t * D_DIM + d4 * 4);
        acc += wt * v;
    }
    float* o = out + (size_t)b * D_DIM + d4 * 4;
    atomicAdd(o + 0, acc.x);
    atomicAdd(o + 1, acc.y);
    atomicAdd(o + 2, acc.z);
    atomicAdd(o + 3, acc.w);
}

extern "C" void kernel_launch(void* const* d_in, const int* in_sizes, int n_in,
                              void* d_out, int out_size, void* d_ws, size_t ws_size,
                              hipStream_t stream) {
    (void)in_sizes; (void)n_in; (void)out_size; (void)ws_size;
    const float* query  = (const float*)d_in[0];
    const float* values = (const float*)d_in[1];
    const float* W1     = (const float*)d_in[2];
    const float* b1     = (const float*)d_in[3];
    const float* W2     = (const float*)d_in[4];
    const float* b2     = (const float*)d_in[5];
    const float* Wv     = (const float*)d_in[6];
    // d_in[7] = bv: softmax is shift-invariant; scores aren't an output -> unused.

    float* out  = (float*)d_out;             // [B,D] context
    float* wout = out + B_SZ * D_DIM;        // [B,T] attention weights

    const size_t VN = (size_t)B_SZ * T_SZ * D_DIM;  // 64M elems
    char* ws = (char*)d_ws;
    unsigned short* vbf = (unsigned short*)ws;                     // 128 MB
    float* scores = (float*)(ws + VN * 2);                         // 256 KB
    float* qpb = scores + 65536;                                   // 128 KB
    unsigned short* W2t = (unsigned short*)(qpb + 32768);          // 2 MB

    vconv2<<<16384, 256, 0, stream>>>(values, vbf);
    w2_transpose<<<dim3(32, 32), dim3(32, 8), 0, stream>>>(W2, W2t);
    qproj2<<<dim3(32, 16), 256, 0, stream>>>(query, W1, b1, b2, qpb);
    score_gemm5<<<512, 512, 0, stream>>>(vbf, W2t, qpb, Wv, scores);
    softmax_z<<<B_SZ, 256, 0, stream>>>(scores, wout, out);
    context_k<<<dim3(B_SZ, 32), 256, 0, stream>>>(values, wout, out);
}